// Round 15
// baseline (315.667 us; speedup 1.0000x reference)
//
#include <hip/hip_runtime.h>
#include <hip/hip_bf16.h>
#include <stdint.h>

#define GCN_N 50000
#define GCN_E 800000
#define GCN_D 256

#define GEMM_BLOCKS ((GCN_N + 63) / 64)     // 782
#define EDGE_BLOCKS ((GCN_E + 255) / 256)   // 3125

// LESSONS ENCODED HERE:
//  - R11/R13/R14 all failed with a 2-pass "chunked" LDS epilogue (same tile
//    written, read, re-written, re-read with no sync between passes). Every
//    1-pass epilogue round passed. DO NOT reuse an LDS tile across passes
//    without an explicit barrier/waitcnt. This file uses only 1-pass epilogues.
//  - ws budget is >= R12's 66MB; this layout is ~64MB (ew eliminated, dc padded).

typedef __attribute__((ext_vector_type(8))) short bf16x8;
typedef __attribute__((ext_vector_type(4))) float f32x4;
typedef unsigned short ushort_t;
typedef unsigned long long u64;

__device__ __forceinline__ float bf2f(ushort_t u) {
    return __uint_as_float(((unsigned)u) << 16);
}
__device__ __forceinline__ ushort_t f2bf(float f) {
    unsigned v = __float_as_uint(f);
    v += 0x7FFFu + ((v >> 16) & 1u);   // round-to-nearest-even
    return (ushort_t)(v >> 16);
}

// edge MLP: Linear(1,8)->ReLU->Linear(8,1)->Sigmoid. Deterministic fp sequence;
// called in fused1 (histogram) and scatter (weight) -> bit-identical results.
__device__ __forceinline__ float edge_w(float a, const float* mw1, const float* mb1,
                                        const float* mw2, const float* mb2) {
    float s = mb2[0];
#pragma unroll
    for (int j = 0; j < 8; ++j) {
        float hj = fmaf(a, mw1[j], mb1[j]);
        hj = fmaxf(hj, 0.0f);
        s = fmaf(hj, mw2[j], s);
    }
    return 1.0f / (1.0f + expf(-s));
}

// direct global->LDS 16B copy (no VGPR round-trip); dest = wave-uniform base + lane*16.
__device__ __forceinline__ void gload_lds16(const void* g, void* l) {
    __builtin_amdgcn_global_load_lds(
        (const __attribute__((address_space(1))) unsigned int*)g,
        (__attribute__((address_space(3))) unsigned int*)l,
        16, 0, 0);
}

__device__ __forceinline__ void split_f32x8(float4 f0, float4 f1, bf16x8& hi, bf16x8& lo) {
    float f[8] = {f0.x, f0.y, f0.z, f0.w, f1.x, f1.y, f1.z, f1.w};
#pragma unroll
    for (int i = 0; i < 8; ++i) {
        unsigned u = __float_as_uint(f[i]);
        hi[i] = (short)(u >> 16);
        float r = f[i] - __uint_as_float(u & 0xFFFF0000u);
        lo[i] = (short)f2bf(r);
    }
}

// W -> bf16 hi/lo fragment-major conversion body (one kt-block of one layer)
__device__ __forceinline__ void wconv_body(const float* __restrict__ W, int kt, int tid,
                                           ushort_t* __restrict__ wtf_hi,
                                           ushort_t* __restrict__ wtf_lo,
                                           ushort_t* smem) {
    ushort_t (*lds_hi)[256] = (ushort_t(*)[256])smem;
    ushort_t (*lds_lo)[256] = (ushort_t(*)[256])(smem + 8192);
    for (int c = 0; c < 32; ++c) {
        float f = W[(kt * 32 + c) * GCN_D + tid];
        unsigned u = __float_as_uint(f);
        lds_hi[c][tid] = (ushort_t)(u >> 16);              // truncation: exact residual
        float r = f - __uint_as_float(u & 0xFFFF0000u);
        lds_lo[c][tid] = f2bf(r);
    }
    __syncthreads();
#pragma unroll
    for (int q = 0; q < 4; ++q) {
        int slot = q * 256 + tid;          // 0..1023 = nt*64 + lane
        int lane = slot & 63, nt = slot >> 6;
        int n = nt * 16 + (lane & 15);
        int kl = (lane >> 4) * 8;
        ushort_t h8[8], l8[8];
#pragma unroll
        for (int j = 0; j < 8; ++j) { h8[j] = lds_hi[kl + j][n]; l8[j] = lds_lo[kl + j][n]; }
        size_t o = ((size_t)(kt * 16 + nt) * 64 + lane) * 8;
#pragma unroll
        for (int j = 0; j < 8; ++j) { wtf_hi[o + j] = h8[j]; wtf_lo[o + j] = l8[j]; }
    }
}

// layer-1 W conversion: must precede fused1 (whose gemm blocks read it).
__global__ __launch_bounds__(256) void wconv1_kernel(const float* __restrict__ W,
                                                     ushort_t* __restrict__ wtf) {
    __shared__ ushort_t smem[16384];
    wconv_body(W, blockIdx.x, threadIdx.x, wtf, wtf + 65536, smem);
}

// ================= fused: gemm_f32(layer1) | edge_mlp | wconvert(L2,L3) ==========
// R12's exact passing structure; 33792B LDS; 1-pass 264-stride epilogue.

__global__ __launch_bounds__(256) void fused1_kernel(
        const float* __restrict__ x, const ushort_t* __restrict__ wtf_hi1,
        const ushort_t* __restrict__ wtf_lo1, const float* __restrict__ b1,
        ushort_t* __restrict__ out_h,
        const float* __restrict__ attr, const int* __restrict__ dst,
        const float* __restrict__ mw1, const float* __restrict__ mb1,
        const float* __restrict__ mw2, const float* __restrict__ mb2,
        u64* __restrict__ dc, int* __restrict__ rank,
        const float* __restrict__ W2, const float* __restrict__ W3,
        ushort_t* __restrict__ wtf) {
    __shared__ ushort_t smem[4 * 16 * 264];   // 33792B
    const int b = blockIdx.x;
    const int tid = threadIdx.x;

    if (b < GEMM_BLOCKS) {
        // ---- gemm_f32: 64 rows x 256 cols, split-precision, gload_lds-staged B ----
        const int lane = tid & 63;
        const int wv   = tid >> 6;
        const int r16  = lane & 15;
        const int kg   = lane >> 4;
        const int row0 = b * 64 + wv * 16;

        f32x4 acc[16];
#pragma unroll
        for (int nt = 0; nt < 16; ++nt) acc[nt] = (f32x4){0.f, 0.f, 0.f, 0.f};

        const int arow = row0 + r16;
        const float* ap = (arow < GCN_N) ? &x[(size_t)arow * GCN_D + kg * 8] : nullptr;
        bf16x8* sH = (bf16x8*)smem;        // 1024 frags (16KB)
        bf16x8* sL = ((bf16x8*)smem) + 1024;

#pragma unroll 1
        for (int kt = 0; kt < 8; ++kt) {
            const bf16x8* gh = (const bf16x8*)wtf_hi1 + (size_t)kt * 1024;
            const bf16x8* gl = (const bf16x8*)wtf_lo1 + (size_t)kt * 1024;
#pragma unroll
            for (int c = 0; c < 4; ++c) {
                gload_lds16(gh + c * 256 + tid, sH + c * 256 + tid);
                gload_lds16(gl + c * 256 + tid, sL + c * 256 + tid);
            }
            float4 f0 = make_float4(0.f, 0.f, 0.f, 0.f), f1 = f0;
            if (ap) {
                f0 = *(const float4*)(ap + kt * 32);
                f1 = *(const float4*)(ap + kt * 32 + 4);
            }
            bf16x8 a_hi, a_lo;
            split_f32x8(f0, f1, a_hi, a_lo);
            __syncthreads();   // drains vmcnt -> staging complete
#pragma unroll
            for (int nt = 0; nt < 16; ++nt) {
                bf16x8 bh = sH[nt * 64 + lane];
                bf16x8 bl = sL[nt * 64 + lane];
                acc[nt] = __builtin_amdgcn_mfma_f32_16x16x32_bf16(a_hi, bh, acc[nt], 0, 0, 0);
                acc[nt] = __builtin_amdgcn_mfma_f32_16x16x32_bf16(a_lo, bh, acc[nt], 0, 0, 0);
                acc[nt] = __builtin_amdgcn_mfma_f32_16x16x32_bf16(a_hi, bl, acc[nt], 0, 0, 0);
            }
            __syncthreads();
        }

        // 1-pass epilogue (264-stride, whole 256-col row per read pass)
        ushort_t* my = smem + wv * (16 * 264);
#pragma unroll
        for (int nt = 0; nt < 16; ++nt) {
            float bv = b1[nt * 16 + r16];
#pragma unroll
            for (int r = 0; r < 4; ++r)
                my[(kg * 4 + r) * 264 + nt * 16 + r16] = f2bf(acc[nt][r] + bv);
        }
#pragma unroll 4
        for (int r = 0; r < 16; ++r) {
            int row = row0 + r;
            if (row < GCN_N) {
                ushort4 v = *(ushort4*)&my[r * 264 + lane * 4];
                *(ushort4*)&out_h[(size_t)row * GCN_D + lane * 4] = v;
            }
        }
    } else if (b < GEMM_BLOCKS + EDGE_BLOCKS) {
        // ---- edge mlp; dc padded 1 node/32B (atomic line-serialization 8 -> 2/line) ----
        int e = (b - GEMM_BLOCKS) * 256 + tid;
        if (e >= GCN_E) return;
        float w = edge_w(attr[e], mw1, mb1, mw2, mb2);
        u64 pack = (1ull << 40) + (u64)((double)w * 4294967296.0);
        u64 old = atomicAdd(&dc[(size_t)dst[e] * 4], pack);
        rank[e] = (int)(old >> 40);
    } else {
        const int wb = b - GEMM_BLOCKS - EDGE_BLOCKS;   // 0..15
        const int layer = 1 + (wb >> 3);                // 1 or 2
        const int kt = wb & 7;
        const float* W = (layer == 1) ? W2 : W3;
        ushort_t* wtf_hi = wtf + (size_t)layer * 2 * 65536;
        wconv_body(W, kt, tid, wtf_hi, wtf_hi + 65536, smem);
    }
}

// ---------------- preprocessing (post-fused) ----------------

// block scan over counts (padded dc) + node normalization terms
__global__ __launch_bounds__(1024) void scan1_kernel(const u64* __restrict__ dc,
                                                     int* __restrict__ part,
                                                     int* __restrict__ bsum,
                                                     float* __restrict__ dinv,
                                                     float* __restrict__ invdeg, int n) {
    __shared__ int s[1024];
    int tid = threadIdx.x;
    int i = blockIdx.x * 1024 + tid;
    u64 dv = (i < n) ? dc[(size_t)i * 4] : 0ull;
    int v = (int)(dv >> 40);
    s[tid] = v;
    if (i < n) {
        float wsum = (float)((double)(dv & ((1ull << 40) - 1)) * (1.0 / 4294967296.0));
        float d = 1.0f + wsum;
        dinv[i] = rsqrtf(d);
        invdeg[i] = 1.0f / d;
    }
    __syncthreads();
#pragma unroll
    for (int d = 1; d < 1024; d <<= 1) {
        int t = (tid >= d) ? s[tid - d] : 0;
        __syncthreads();
        s[tid] += t;
        __syncthreads();
    }
    if (i < n) part[i] = s[tid] - v;  // exclusive within block
    if (tid == 1023) bsum[blockIdx.x] = s[1023];
}

// wave64 shuffle scan over block sums (nb <= 64)
__global__ void scan2_kernel(int* bsum, int nb) {
    int t = threadIdx.x;
    int orig = (t < nb) ? bsum[t] : 0;
    int v = orig;
#pragma unroll
    for (int d = 1; d < 64; d <<= 1) {
        int u = __shfl_up(v, d, 64);
        if (t >= d) v += u;
    }
    if (t < nb) bsum[t] = v - orig;   // exclusive
}

__global__ void scan3_kernel(const int* __restrict__ part, const int* __restrict__ bsum,
                             int* __restrict__ offs, int n, int e_total) {
    int i = blockIdx.x * blockDim.x + threadIdx.x;
    if (i < n) offs[i] = part[i] + bsum[i >> 10];
    if (i == 0) offs[n] = e_total;
}

// no atomics: position = offs[dst] + rank; weight recomputed (bit-identical).
__global__ void scatter_kernel(const int* __restrict__ src, const int* __restrict__ dst,
                               const float* __restrict__ attr,
                               const float* __restrict__ mw1, const float* __restrict__ mb1,
                               const float* __restrict__ mw2, const float* __restrict__ mb2,
                               const float* __restrict__ dinv,
                               const int* __restrict__ offs, const int* __restrict__ rank,
                               int2* __restrict__ csr, int e_count) {
    int e = blockIdx.x * blockDim.x + threadIdx.x;
    if (e >= e_count) return;
    int sN = src[e], dN = dst[e];
    float w0 = edge_w(attr[e], mw1, mb1, mw2, mb2);
    int pos = offs[dN] + rank[e];
    float w = dinv[sN] * w0 * dinv[dN];
    csr[pos] = make_int2(sN, __float_as_int(w));
}

// ---------------- MFMA GEMM (layers 2,3): bf16 A, W_hi only, gload_lds-staged ---------
// R12's exact passing structure (kt-pair staging, 1-pass 264 epilogue).

__global__ __launch_bounds__(256) void mfma_gemm_bf16_kernel(
        const ushort_t* __restrict__ a_in,
        const ushort_t* __restrict__ wtf_hi,
        const float* __restrict__ bias,
        ushort_t* __restrict__ out_h,
        int n_rows) {
    __shared__ ushort_t smem[4 * 16 * 264];   // 33792B >= 32KB stage area
    const int tid  = threadIdx.x;
    const int lane = tid & 63;
    const int wv   = tid >> 6;
    const int r16  = lane & 15;
    const int kg   = lane >> 4;
    const int row0 = blockIdx.x * 64 + wv * 16;

    f32x4 acc[16];
#pragma unroll
    for (int nt = 0; nt < 16; ++nt) acc[nt] = (f32x4){0.f, 0.f, 0.f, 0.f};

    const int arow = row0 + r16;
    const ushort_t* ap = (arow < n_rows) ? &a_in[(size_t)arow * GCN_D + kg * 8] : nullptr;
    bf16x8* sH = (bf16x8*)smem;               // 2048 fragments (32KB)

#pragma unroll 1
    for (int kp = 0; kp < 4; ++kp) {          // kt pair
        const bf16x8* gh = (const bf16x8*)wtf_hi + (size_t)kp * 2048;
#pragma unroll
        for (int j = 0; j < 8; ++j)
            gload_lds16(gh + j * 256 + tid, sH + j * 256 + tid);
        bf16x8 a0 = (bf16x8){0,0,0,0,0,0,0,0}, a1 = a0;
        if (ap) {
            a0 = *(const bf16x8*)(ap + (kp * 2) * 32);
            a1 = *(const bf16x8*)(ap + (kp * 2 + 1) * 32);
        }
        __syncthreads();   // drains vmcnt -> staging complete
#pragma unroll
        for (int nt = 0; nt < 16; ++nt) {
            bf16x8 bh0 = sH[nt * 64 + lane];
            bf16x8 bh1 = sH[1024 + nt * 64 + lane];
            acc[nt] = __builtin_amdgcn_mfma_f32_16x16x32_bf16(a0, bh0, acc[nt], 0, 0, 0);
            acc[nt] = __builtin_amdgcn_mfma_f32_16x16x32_bf16(a1, bh1, acc[nt], 0, 0, 0);
        }
        __syncthreads();
    }

    ushort_t* my = smem + wv * (16 * 264);
#pragma unroll
    for (int nt = 0; nt < 16; ++nt) {
        float bv = bias[nt * 16 + r16];
#pragma unroll
        for (int r = 0; r < 4; ++r)
            my[(kg * 4 + r) * 264 + nt * 16 + r16] = f2bf(acc[nt][r] + bv);
    }
#pragma unroll 4
    for (int r = 0; r < 16; ++r) {
        int row = row0 + r;
        if (row < n_rows) {
            ushort4 v = *(ushort4*)&my[r * 264 + lane * 4];
            *(ushort4*)&out_h[(size_t)row * GCN_D + lane * 4] = v;
        }
    }
}

// ---------------- SpMM: agg = A_norm*h + diag(1/deg)*h ----------------

template <int OUT_BF16>
__global__ __launch_bounds__(256) void spmm_kernel(const ushort_t* __restrict__ h,
                                                   const int* __restrict__ offs,
                                                   const int2* __restrict__ csr,
                                                   const float* __restrict__ invdeg,
                                                   void* __restrict__ outp, int n) {
    int wid = (blockIdx.x * blockDim.x + threadIdx.x) >> 6;
    int lane = threadIdx.x & 63;
    if (wid >= n) return;
    const ushort4* h4 = (const ushort4*)h;
    ushort4 sv = h4[(size_t)wid * 64 + lane];
    float sw = invdeg[wid];
    float4 acc;
    acc.x = bf2f(sv.x) * sw; acc.y = bf2f(sv.y) * sw;
    acc.z = bf2f(sv.z) * sw; acc.w = bf2f(sv.w) * sw;
    int e0 = offs[wid], e1 = offs[wid + 1];
    int k = e0;
    for (; k + 8 <= e1; k += 8) {
        int2 ee[8]; ushort4 vv[8];
#pragma unroll
        for (int u = 0; u < 8; ++u) ee[u] = csr[k + u];
#pragma unroll
        for (int u = 0; u < 8; ++u) vv[u] = h4[(size_t)ee[u].x * 64 + lane];
#pragma unroll
        for (int u = 0; u < 8; ++u) {
            float w = __int_as_float(ee[u].y);
            acc.x = fmaf(w, bf2f(vv[u].x), acc.x);
            acc.y = fmaf(w, bf2f(vv[u].y), acc.y);
            acc.z = fmaf(w, bf2f(vv[u].z), acc.z);
            acc.w = fmaf(w, bf2f(vv[u].w), acc.w);
        }
    }
    for (; k < e1; ++k) {
        int2 e = csr[k];
        float w = __int_as_float(e.y);
        ushort4 hv = h4[(size_t)e.x * 64 + lane];
        acc.x = fmaf(w, bf2f(hv.x), acc.x);
        acc.y = fmaf(w, bf2f(hv.y), acc.y);
        acc.z = fmaf(w, bf2f(hv.z), acc.z);
        acc.w = fmaf(w, bf2f(hv.w), acc.w);
    }
    if (OUT_BF16) {
        ushort4 o;
        o.x = f2bf(fmaxf(acc.x, 0.f));
        o.y = f2bf(fmaxf(acc.y, 0.f));
        o.z = f2bf(fmaxf(acc.z, 0.f));
        o.w = f2bf(fmaxf(acc.w, 0.f));
        ((ushort4*)outp)[(size_t)wid * 64 + lane] = o;
    } else {
        ((float4*)outp)[(size_t)wid * 64 + lane] = acc;
    }
}

// ---------------- launch ----------------

extern "C" void kernel_launch(void* const* d_in, const int* in_sizes, int n_in,
                              void* d_out, int out_size, void* d_ws, size_t ws_size,
                              hipStream_t stream) {
    const float* x    = (const float*)d_in[0];
    const int*   ei   = (const int*)d_in[1];
    const float* attr = (const float*)d_in[2];
    const float* W1 = (const float*)d_in[3];  const float* b1 = (const float*)d_in[4];
    const float* W2 = (const float*)d_in[5];  const float* b2 = (const float*)d_in[6];
    const float* W3 = (const float*)d_in[7];  const float* b3 = (const float*)d_in[8];
    const float* mw1 = (const float*)d_in[9]; const float* mb1 = (const float*)d_in[10];
    const float* mw2 = (const float*)d_in[11];const float* mb2 = (const float*)d_in[12];
    float* out = (float*)d_out;

    const int N = GCN_N, E = GCN_E;
    const int* srcI = ei;
    const int* dstI = ei + E;

    // ws layout (~64 MB total; R12's 66MB proved the budget is >= 66MB)
    char* ws = (char*)d_ws;
    int*   rank   = (int*)ws;                        ws += (size_t)E * 4;        // 3.2MB
    u64*   dc     = (u64*)(((uintptr_t)ws + 255) & ~(uintptr_t)255);
    ws = (char*)(dc + (size_t)N * 4);                                            // 1.6MB
    float* dinv   = (float*)ws;                      ws += (size_t)N * 4;
    float* invdeg = (float*)ws;                      ws += (size_t)N * 4;
    int*   offs   = (int*)ws;                        ws += (size_t)(N + 1) * 4;
    int*   bsum   = (int*)ws;                        ws += 64 * 4;
    int*   part   = (int*)ws;                        ws += (size_t)N * 4;
    int2*  csr    = (int2*)(((uintptr_t)ws + 255) & ~(uintptr_t)255);
    ws = (char*)(csr + E);                                                       // 6.4MB
    ushort_t* h   = (ushort_t*)(((uintptr_t)ws + 255) & ~(uintptr_t)255);        // 25.6MB
    ws = (char*)(h + (size_t)N * GCN_D);
    ushort_t* act = (ushort_t*)(((uintptr_t)ws + 255) & ~(uintptr_t)255);        // 25.6MB
    ws = (char*)(act + (size_t)N * GCN_D);
    ushort_t* wtf = (ushort_t*)(((uintptr_t)ws + 255) & ~(uintptr_t)255);        // 0.79MB
    ushort_t* wtf_hi1 = wtf;
    ushort_t* wtf_lo1 = wtf + 65536;
    ushort_t* wtf_hi2 = wtf + 2 * 65536;
    ushort_t* wtf_hi3 = wtf + 4 * 65536;

    hipMemsetAsync(dc, 0, (size_t)N * 4 * sizeof(u64), stream);
    wconv1_kernel<<<8, 256, 0, stream>>>(W1, wtf);
    fused1_kernel<<<GEMM_BLOCKS + EDGE_BLOCKS + 16, 256, 0, stream>>>(
        x, wtf_hi1, wtf_lo1, b1, h,
        attr, dstI, mw1, mb1, mw2, mb2, dc, rank,
        W2, W3, wtf);
    int nb = (N + 1023) / 1024;
    scan1_kernel<<<nb, 1024, 0, stream>>>(dc, part, bsum, dinv, invdeg, N);
    scan2_kernel<<<1, 64, 0, stream>>>(bsum, nb);
    scan3_kernel<<<(N + 255) / 256, 256, 0, stream>>>(part, bsum, offs, N, E);
    scatter_kernel<<<(E + 255) / 256, 256, 0, stream>>>(srcI, dstI, attr,
                                                        mw1, mb1, mw2, mb2, dinv,
                                                        offs, rank, csr, E);

    const int gemm_grid = (N + 63) / 64;
    const int spmm_grid = (N * 64 + 255) / 256;

    // layer 1 spmm (h computed inside fused1)
    spmm_kernel<1><<<spmm_grid, 256, 0, stream>>>(h, offs, csr, invdeg, act, N);
    // layer 2
    mfma_gemm_bf16_kernel<<<gemm_grid, 256, 0, stream>>>(act, wtf_hi2, b2, h, N);
    spmm_kernel<1><<<spmm_grid, 256, 0, stream>>>(h, offs, csr, invdeg, act, N);
    // layer 3
    mfma_gemm_bf16_kernel<<<gemm_grid, 256, 0, stream>>>(act, wtf_hi3, b3, h, N);
    spmm_kernel<0><<<spmm_grid, 256, 0, stream>>>(h, offs, csr, invdeg, out, N);
}